// Round 13
// baseline (204.134 us; speedup 1.0000x reference)
//
#include <hip/hip_runtime.h>
#include <cstdint>
#include <cstddef>

#define ALPHA 0.01f
#define A1    0.99f
#define B_    8
#define S_    2048
#define H_    2048
#define NCH   8      // chunks along S
#define CL    256    // chunk length
#define NKT   64     // K tiles in GEMM (2048/32)

typedef __attribute__((ext_vector_type(8))) short bf16x8;
typedef __attribute__((ext_vector_type(4))) float f32x4;

__device__ __forceinline__ unsigned short f2bf(float f) {
    unsigned int u = __float_as_uint(f);
    u += 0x7FFFu + ((u >> 16) & 1u);   // round-to-nearest-even
    return (unsigned short)(u >> 16);
}

__device__ __forceinline__ void gld16(const void* g, void* l) {
    __builtin_amdgcn_global_load_lds(
        (const __attribute__((address_space(1))) unsigned int*)g,
        (__attribute__((address_space(3))) unsigned int*)l, 16, 0, 0);
}

// ---------------- W cast: f32 -> bf16 ----------------
__global__ void ema_cast_w(const float* __restrict__ W, short* __restrict__ Wb) {
    int i = (blockIdx.x * 256 + threadIdx.x) * 4;
    float4 v = *(const float4*)(W + i);
    short4 o;
    o.x = (short)f2bf(v.x);
    o.y = (short)f2bf(v.y);
    o.z = (short)f2bf(v.z);
    o.w = (short)f2bf(v.w);
    *(short4*)(Wb + i) = o;
}

// ---------------- pass 1: chunk-local EMA carries (float2, 2 chains/thread) ----
__global__ __launch_bounds__(256) void ema_carry_kernel(
        const float* __restrict__ x, float* __restrict__ carry) {
    int bid = blockIdx.x;                 // 256 blocks: b(8) x c(8) x hg(4)
    int hg = bid & 3;
    int c  = (bid >> 2) & 7;
    int b  = bid >> 5;
    int h0 = (hg << 9) + (threadIdx.x << 1);
    const float2* px = (const float2*)(x + ((size_t)(b * S_) + (size_t)c * CL) * H_ + h0);
    const int STR = H_ / 2;               // float2 stride per sequence step
    float s0, s1;
    int i0;
    if (c == 0) { float2 v = px[0]; s0 = v.x; s1 = v.y; i0 = 1; }
    else        { s0 = 0.f; s1 = 0.f;                   i0 = 0; }
    #pragma unroll 8
    for (int i = i0; i < CL; ++i) {
        float2 v = px[(size_t)i * STR];
        s0 = fmaf(A1, s0, ALPHA * v.x);
        s1 = fmaf(A1, s1, ALPHA * v.y);
    }
    *(float2*)(carry + ((b << 3) + c) * H_ + h0) = (float2){s0, s1};
}

// ---------------- pass 2: apply carry-in, rescan, write packed bf16 s ----------
__global__ __launch_bounds__(256) void ema_apply_kernel(
        const float* __restrict__ x, const float* __restrict__ carry,
        unsigned short* __restrict__ sb) {
    int bid = blockIdx.x;                 // 256 blocks: b(8) x c(8) x hg(4)
    int hg = bid & 3;
    int c  = (bid >> 2) & 7;
    int b  = bid >> 5;
    int h0 = (hg << 9) + (threadIdx.x << 1);

    float A256 = A1;                      // 0.99^256 via 8 squarings
    #pragma unroll
    for (int q = 0; q < 8; ++q) A256 *= A256;

    float c0 = 0.f, c1 = 0.f, f = 1.f;
    for (int j = c - 1; j >= 0; --j) {
        float2 cv = *(const float2*)(carry + ((b << 3) + j) * H_ + h0);
        c0 = fmaf(cv.x, f, c0);
        c1 = fmaf(cv.y, f, c1);
        f *= A256;
    }

    size_t base = ((size_t)(b * S_) + (size_t)c * CL) * H_ + h0;
    const float2* px = (const float2*)(x + base);
    unsigned int*  pu = (unsigned int*)(sb + base);
    const int STR = H_ / 2;
    float s0, s1;
    int i0;
    if (c == 0) {
        float2 v = px[0]; s0 = v.x; s1 = v.y;
        pu[0] = (unsigned int)f2bf(s0) | ((unsigned int)f2bf(s1) << 16);
        i0 = 1;
    } else { s0 = c0; s1 = c1; i0 = 0; }
    #pragma unroll 8
    for (int i = i0; i < CL; ++i) {
        float2 v = px[(size_t)i * STR];
        s0 = fmaf(A1, s0, ALPHA * v.x);
        s1 = fmaf(A1, s1, ALPHA * v.y);
        pu[(size_t)i * STR] = (unsigned int)f2bf(s0) | ((unsigned int)f2bf(s1) << 16);
    }
}

// ---------------- GEMM: 256x256 tile, BK=32, 8 waves, 3-buffer, 1 BAR/tile ----
// out[m,n] = sum_k s[m,k]*W[n,k] + bias[n].  M=16384 N=2048 K=2048.
// Per K-tile: {12 ds_reads up-front; 4 gld stage(t+2); 32 MFMA; VMW(4); BAR}.
// 3 LDS buffers (96 KiB): stage(t+2) targets buf (t+2)%3 = buf read in tile
// t-1 -> all its reads completed before owners passed BAR(t-1) -> one
// end-of-tile barrier is sufficient; waves drift freely within a tile so
// ds_reads of one wave overlap MFMA of another. VMW(4) per wave forces its
// own t+1-batch slice; BAR (asm, "memory" clobber: compiler fence WITHOUT
// hardware waitcnt drain) publishes it.
// 64B rows; swizzle col16 ^= (row&3), both-sides; worst 2-way alias (free).

#define BARM asm volatile("s_barrier" ::: "memory")
#define VMW(n) asm volatile("s_waitcnt vmcnt(" #n ")" ::: "memory")

#define STG(kt, buf) do {                                                          \
    gld16(gA0 + (size_t)(kt) * 64, &ldsA[buf][(w << 9)]);                          \
    gld16(gA1 + (size_t)(kt) * 64, &ldsA[buf][4096 + (w << 9)]);                   \
    gld16(gB0 + (size_t)(kt) * 64, &ldsB[buf][(w << 9)]);                          \
    gld16(gB1 + (size_t)(kt) * 64, &ldsB[buf][4096 + (w << 9)]); } while (0)

// A frags: rows wm*128 + mh*64 + m*16 + (lane&15); 64B rows; swizzled ck
#define LDA(dst, mh) do {                                                          \
    const char* base_ = (const char*)&ldsA[bc][0] + (wm << 13) + ((mh) << 12)      \
                        + laneRow + ck;                                            \
    _Pragma("unroll") for (int m_ = 0; m_ < 4; ++m_)                               \
        dst[m_] = *(const bf16x8*)(base_ + (m_ << 10)); } while (0)

// B frags: rows wn*64 + n*16 + (lane&15)
#define LDB do {                                                                   \
    const char* base_ = (const char*)&ldsB[bc][0] + (wn << 12) + laneRow + ck;     \
    _Pragma("unroll") for (int n_ = 0; n_ < 4; ++n_)                               \
        Bf[n_] = *(const bf16x8*)(base_ + (n_ << 10)); } while (0)

#define MM(Asrc, mh, nh) do { __builtin_amdgcn_s_setprio(1);                       \
    _Pragma("unroll") for (int m_ = 0; m_ < 4; ++m_)                               \
    _Pragma("unroll") for (int n_ = 0; n_ < 2; ++n_)                               \
        acc[(mh) * 4 + m_][(nh) * 2 + n_] = __builtin_amdgcn_mfma_f32_16x16x32_bf16( \
            Asrc[m_], Bf[(nh) * 2 + n_], acc[(mh) * 4 + m_][(nh) * 2 + n_], 0, 0, 0); \
    __builtin_amdgcn_s_setprio(0); } while (0)

__global__ __launch_bounds__(512, 2) void ema_gemm_kernel(
        const short* __restrict__ Sb, const short* __restrict__ Wb,
        const float* __restrict__ bias, float* __restrict__ out) {
    __shared__ short ldsA[3][8192];    // 3 x 16 KiB (256 rows x 32 cols bf16)
    __shared__ short ldsB[3][8192];    // 3 x 16 KiB

    int bid = blockIdx.x;
    int swz = ((bid & 7) << 6) | (bid >> 3);   // XCD swizzle, bijective (512 % 8 == 0)
    int tm = swz >> 3;                 // 0..63
    int tn = swz & 7;                  // 0..7

    int tid  = threadIdx.x;
    int lane = tid & 63;
    int w    = tid >> 6;               // 0..7
    int wm   = w >> 2;                 // 0..1
    int wn   = w & 3;                  // 0..3

    const int K2 = H_ * 2;             // row stride in bytes (4096)
    int rowA = tm << 8;
    int rowB = tn << 8;

    // ---- staging source pointers (pre-swizzled global addresses) ----
    // staged LDS row R = issue*128 + 16w + (lane>>2); col16 = lane&3
    // LDS[R][c] holds global[R][c ^ (R&3)]; R&3 = (lane>>2)&3
    int strow = (w << 4) + (lane >> 2);
    int colb  = (((lane & 3) ^ ((lane >> 2) & 3)) << 4);
    const char* gA0 = (const char*)Sb + (size_t)(rowA + strow) * K2 + colb;
    const char* gA1 = (const char*)Sb + (size_t)(rowA + 128 + strow) * K2 + colb;
    const char* gB0 = (const char*)Wb + (size_t)(rowB + strow) * K2 + colb;
    const char* gB1 = (const char*)Wb + (size_t)(rowB + 128 + strow) * K2 + colb;

    // ---- fragment ds_read offsets: frag row&3 = lane&3 ----
    int laneRow = (lane & 15) << 6;
    int ck = ((lane >> 4) ^ (lane & 3)) << 4;

    f32x4 acc[8][4];
    #pragma unroll
    for (int i = 0; i < 8; ++i)
        #pragma unroll
        for (int j = 0; j < 4; ++j)
            acc[i][j] = (f32x4){0.f, 0.f, 0.f, 0.f};
    bf16x8 Af0[4], Af1[4], Bf[4];

    int colg = (tn << 8) + (wn << 6) + (lane & 15);
    float bb[4];
    #pragma unroll
    for (int n = 0; n < 4; ++n) bb[n] = bias[colg + (n << 4)];

    // ---- prologue: stage tiles 0 and 1 (4 loads each); force tile 0 ----
    STG(0, 0);
    STG(1, 1);
    VMW(4);
    BARM;

    int bc = 0, bs = 2;                // read buffer, stage buffer ((t+2)%3)
    for (int t = 0; t < NKT; ++t) {
        // all 12 ds_reads up-front: Af1 drains under MM(0,*)
        LDA(Af0, 0); LDB; LDA(Af1, 1);
        if (t < NKT - 2) { STG(t + 2, bs); }
        MM(Af0, 0, 0);
        MM(Af0, 0, 1);
        MM(Af1, 1, 0);
        MM(Af1, 1, 1);
        if (t < NKT - 2)       { VMW(4); }   // forces tile t+1's 4-load batch
        else if (t == NKT - 2) { VMW(0); }   // drain for the last tile
        BARM;
        bc = (bc == 2) ? 0 : bc + 1;
        bs = (bs == 2) ? 0 : bs + 1;
    }

    // ---- epilogue: C/D layout col=lane&15, row=(lane>>4)*4+q ----
    int rowg = (tm << 8) + (wm << 7) + ((lane >> 4) << 2);
    #pragma unroll
    for (int m = 0; m < 8; ++m) {
        #pragma unroll
        for (int n = 0; n < 4; ++n) {
            int c = colg + (n << 4);
            size_t rb = (size_t)(rowg + (m << 4)) << 11;
            #pragma unroll
            for (int q = 0; q < 4; ++q)
                out[rb + ((size_t)q << 11) + c] = acc[m][n][q] + bb[n];
        }
    }
}

extern "C" void kernel_launch(void* const* d_in, const int* in_sizes, int n_in,
                              void* d_out, int out_size, void* d_ws, size_t ws_size,
                              hipStream_t stream) {
    const float* x    = (const float*)d_in[0];   // [B,S,H] f32
    const float* W    = (const float*)d_in[1];   // [H,H] f32
    const float* bias = (const float*)d_in[2];   // [H] f32
    float* out = (float*)d_out;                  // [B,S,H] f32

    char* ws = (char*)d_ws;
    size_t s_bytes = (size_t)B_ * S_ * H_ * 2;   // 67.1 MB bf16 s
    size_t w_bytes = (size_t)H_ * H_ * 2;        // 8.4 MB bf16 W
    unsigned short* s_bf  = (unsigned short*)ws;
    short*          w_bf  = (short*)(ws + s_bytes);
    float*          carry = (float*)(ws + s_bytes + w_bytes);  // 8*8*2048 f32

    ema_cast_w<<<(H_ * H_) / 1024, 256, 0, stream>>>(W, w_bf);
    ema_carry_kernel<<<B_ * NCH * (H_ / 512), 256, 0, stream>>>(x, carry);
    ema_apply_kernel<<<B_ * NCH * (H_ / 512), 256, 0, stream>>>(x, carry, s_bf);
    ema_gemm_kernel<<<(16384 / 256) * (2048 / 256), 512, 0, stream>>>(
        (const short*)s_bf, w_bf, bias, out);
}